// Round 5
// baseline (491.225 us; speedup 1.0000x reference)
//
#include <hip/hip_runtime.h>

#define NTHREADS 256
#define TILE 40          // output tile per wave
#define RG   64          // region = TILE + 2*12 (halo 12)
#define NITER 11         // 1 initial + NUM_ITER=10
#define IMG  1024
#define NT   26          // ceil(1024/40)
#define NWAVE (NTHREADS/64)

// Wave-autonomous soft-skeleton: each wave owns a 40x40 tile; lane = region
// column; column data lives in registers. No LDS, no barriers.
// ws[0]=sum(skel_pred*target) ws[1]=sum(skel_pred)
// ws[2]=sum(skel_target*sigmoid(pred)) ws[3]=sum(skel_target)
__global__ __launch_bounds__(NTHREADS, 3)
void cldice_main(const float* __restrict__ pred,
                 const float* __restrict__ target,
                 double* __restrict__ ws)
{
    const int tid  = threadIdx.x;
    const int lane = tid & 63;
    const int wid  = blockIdx.x * NWAVE + (tid >> 6);   // 0..10815
    const int tx = wid % NT;
    const int t2 = wid / NT;
    const int ty = t2 % NT;
    const int zp = t2 / NT;            // 0..15
    const int b = zp >> 1, phase = zp & 1;

    const int ox = tx * TILE - 12;
    const int oy = ty * TILE - 12;
    const size_t base = (size_t)b * (size_t)(IMG * IMG);
    const float* __restrict__ src = phase ? target : pred;
    const float* __restrict__ oth = phase ? pred : target;

    const float PINF =  __builtin_huge_valf();
    const float NINF = -PINF;

    const int gx = ox + lane;
    const bool colOK = (unsigned)gx < (unsigned)IMG;

    // ---- load column into registers; image-OOB -> +inf (erode pad identity)
    float e[RG];
#pragma unroll
    for (int j = 0; j < RG; ++j) {
        const int gy = oy + j;
        float v = PINF;
        if (colOK && (unsigned)gy < (unsigned)IMG) {
            v = src[base + (size_t)gy * IMG + gx];
            if (!phase) v = 1.0f / (1.0f + __expf(-v));
        }
        e[j] = v;
    }

    float skel[TILE];
#pragma unroll
    for (int k = 0; k < TILE; ++k) skel[k] = 0.0f;

    // Invariant at iteration start: e[] holds +inf at image-OOB positions.
    // Valid region rows/cols shrink by 1 per erosion; interior [12,51] needs
    // er rows/cols [11,52] at it=10 -> exactly the valid set.
#pragma unroll 1
    for (int it = 0; it < NITER; ++it) {
        float ep = e[0];     // e_orig[j-1]
        float ec = e[1];     // e_orig[j]
        float ner_pp = NINF, ner_p = NINF;   // -inf-masked er[j-2], er[j-1]
#pragma unroll
        for (int j = 1; j <= 62; ++j) {
            const float en = e[j + 1];                    // e_orig[j+1]
            // erode: vertical then horizontal 3-min (pads +inf via invariant)
            const float vm  = fminf(fminf(ep, ec), en);
            const float erj = fminf(fminf(__shfl_up(vm, 1), vm),
                                    __shfl_down(vm, 1));
            const int  gy  = oy + j;
            const bool okj = colOK && ((unsigned)gy < (unsigned)IMG);

            if (j >= 11 && j <= 52) {
                // open input: er with image-OOB -> -inf (maxpool pad)
                const float nerj = okj ? erj : NINF;
                if (j >= 13) {
                    // open[j-1] = hmax3(vmax3(ner[j-2..j]))
                    const float om = fmaxf(fmaxf(ner_pp, ner_p), nerj);
                    const float op = fmaxf(fmaxf(__shfl_up(om, 1), om),
                                           __shfl_down(om, 1));
                    const float d  = fmaxf(ep - op, 0.0f);  // ep = e_orig[j-1]
                    const int   k  = j - 13;                // region row j-1
                    skel[k] += fmaxf(fmaf(-skel[k], d, d), 0.0f);
                }
                ner_pp = ner_p; ner_p = nerj;
            }
            // e_next = er; restore +inf at OOB for next iteration's erode
            e[j] = okj ? erj : PINF;
            ep = ec; ec = en;
        }
    }

    // ---- sums over interior (region rows 12..51, lanes 12..51)
    float spf = 0.0f, ssf = 0.0f;
    const bool laneIn = (lane >= 12) && (lane <= 51) && colOK;
#pragma unroll
    for (int k = 0; k < TILE; ++k) {
        const int gy = oy + 12 + k;
        if (laneIn && (unsigned)gy < (unsigned)IMG) {
            float x = oth[base + (size_t)gy * IMG + gx];
            if (phase) x = 1.0f / (1.0f + __expf(-x));   // pred_prob
            spf += skel[k] * x;
            ssf += skel[k];
        }
    }
    double sp = (double)spf, ss = (double)ssf;
#pragma unroll
    for (int off = 32; off > 0; off >>= 1) {
        sp += __shfl_down(sp, off);
        ss += __shfl_down(ss, off);
    }
    if (lane == 0) {
        atomicAdd(&ws[phase * 2],     sp);
        atomicAdd(&ws[phase * 2 + 1], ss);
    }
}

__global__ void cldice_zero(double* __restrict__ ws) {
    if (threadIdx.x < 4) ws[threadIdx.x] = 0.0;
}

__global__ void cldice_final(const double* __restrict__ ws,
                             float* __restrict__ out) {
    if (threadIdx.x == 0 && blockIdx.x == 0) {
        double tprec = (ws[0] + 1.0) / (ws[1] + 1.0);
        double tsens = (ws[2] + 1.0) / (ws[3] + 1.0);
        double cl = 2.0 * tprec * tsens / (tprec + tsens + 1e-7);
        out[0] = (float)(1.0 - cl);
    }
}

extern "C" void kernel_launch(void* const* d_in, const int* in_sizes, int n_in,
                              void* d_out, int out_size, void* d_ws, size_t ws_size,
                              hipStream_t stream) {
    const float* pred   = (const float*)d_in[0];
    const float* target = (const float*)d_in[1];
    double* ws = (double*)d_ws;
    float* out = (float*)d_out;

    const int nwaves = NT * NT * 16;           // 10816
    const int nblocks = nwaves / NWAVE;        // 2704

    cldice_zero<<<dim3(1), dim3(64), 0, stream>>>(ws);
    cldice_main<<<dim3(nblocks), dim3(NTHREADS), 0, stream>>>(pred, target, ws);
    cldice_final<<<dim3(1), dim3(64), 0, stream>>>(ws, out);
}